// Round 2
// baseline (508.065 us; speedup 1.0000x reference)
//
#include <hip/hip_runtime.h>
#include <cmath>

#define NTOK 32768   // 8*4096 tokens
#define EMB  2048
#define NEXP 64
#define TOPK 8
#define BT   128     // tokens per block -> grid 256 = 1 block/CU
#define KC   32      // K per chunk = MFMA K
#define NCH  (EMB / KC)   // 64
#define TAU  1e-4f   // exact-recompute margin (~60 sigma of limb-GEMM error)

typedef __attribute__((ext_vector_type(8))) short bf16x8;   // 8 bf16 (4 VGPRs)
typedef __attribute__((ext_vector_type(4))) float f32x4;

union U4 { unsigned int u[4]; bf16x8 v; };

__device__ __forceinline__ float uf(unsigned int x) { return __uint_as_float(x); }
__device__ __forceinline__ unsigned int fu(float x) { return __float_as_uint(x); }

__device__ __forceinline__ void gld16(const float* g, float* lds) {
    __builtin_amdgcn_global_load_lds(
        (const __attribute__((address_space(1))) void*)g,
        (__attribute__((address_space(3))) void*)lds,
        16, 0, 0);
}

// LDS map (56 KB static):
//   xs[2][128][32] f32   @ 0      (2 x 16 KB)  X chunk, 16B-granule swizzled via global src
//   ws[2][3][4][64][8] u16 @ 32768 (2 x 12 KB) W bf16 limb planes, k-slot-major (conflict-free)
//   lg[128][66] f32      @ 0      (33792 B)    epilogue logits (aliases xs + 1KB of ws buf0;
//                                              safe: written only after final chunk barrier)
__global__ __launch_bounds__(512, 2) void router_bf16x3(
    const float* __restrict__ X,   // [NTOK][EMB]
    const float* __restrict__ W,   // [NEXP][EMB]
    const float* __restrict__ Bv,  // [NEXP]
    float* __restrict__ out)       // probs [NTOK][64], then indices [NTOK][8] as f32
{
    __shared__ __align__(16) unsigned char smem[57344];
    float* xsBase          = (float*)smem;                       // + buf*4096 floats
    unsigned short* wsBase = (unsigned short*)(smem + 32768);    // + buf*6144 ushorts
    float* lg              = (float*)smem;                       // [128][66]

    const int tid  = threadIdx.x;
    const int lane = tid & 63;
    const int w    = tid >> 6;     // 0..7
    const int tg   = w >> 1;       // token group: rows tg*32 .. +31
    const int eh   = w & 1;        // expert half: cols eh*32 .. +31
    const int eL   = lane & 15;
    const int q    = lane >> 4;
    const int t0   = blockIdx.x * BT;

    f32x4 am[4], ac[4];            // [tt*2+cc]: head acc + correction acc
    #pragma unroll
    for (int t = 0; t < 4; ++t) {
        am[t] = (f32x4){0.f, 0.f, 0.f, 0.f};
        ac[t] = (f32x4){0.f, 0.f, 0.f, 0.f};
    }

    // ---- X stage: global_load_lds, dest linear [row][slot], source granule-swizzled
    //      so reads at slot (2q)^(row&7) are conflict-free.
    auto stageX = [&](int ch, int buf) {
        const int kc0 = ch * KC;
        float* dst = xsBase + buf * 4096;
        #pragma unroll
        for (int s = 0; s < 2; ++s) {
            const int instr = w * 2 + s;              // 0..15
            const int row   = instr * 8 + (lane >> 3);
            const int g     = (lane & 7) ^ (lane >> 3);   // src 16B granule (row&7 == lane>>3)
            gld16(&X[(size_t)(t0 + row) * EMB + kc0 + 4 * g], dst + instr * 256);
        }
    };

    // ---- W stage: 1 float4 per thread; split to 3 bf16 limbs; k-slot-major LDS layout
    auto loadW = [&](int ch) -> float4 {
        const int er = tid >> 3;                      // expert row 0..63
        const int h  = tid & 7;                       // 4-f32 granule 0..7
        return *(const float4*)&W[(size_t)er * EMB + ch * KC + 4 * h];
    };
    auto putW = [&](float4 v, int buf) {
        const int er = tid >> 3, h = tid & 7, slot = h >> 1, sub = h & 1;
        unsigned short* base = wsBase + buf * 6144;
        unsigned int u0 = fu(v.x), u1 = fu(v.y), u2 = fu(v.z), u3 = fu(v.w);
        unsigned int p1a = (u0 >> 16) | (u1 & 0xffff0000u);
        unsigned int p1b = (u2 >> 16) | (u3 & 0xffff0000u);
        float r0 = v.x - uf(u0 & 0xffff0000u), r1 = v.y - uf(u1 & 0xffff0000u);
        float r2 = v.z - uf(u2 & 0xffff0000u), r3 = v.w - uf(u3 & 0xffff0000u);
        unsigned int w0 = fu(r0), w1 = fu(r1), w2 = fu(r2), w3 = fu(r3);
        unsigned int p2a = (w0 >> 16) | (w1 & 0xffff0000u);
        unsigned int p2b = (w2 >> 16) | (w3 & 0xffff0000u);
        float s0 = r0 - uf(w0 & 0xffff0000u), s1 = r1 - uf(w1 & 0xffff0000u);
        float s2 = r2 - uf(w2 & 0xffff0000u), s3 = r3 - uf(w3 & 0xffff0000u);
        unsigned int p3a = (fu(s0) >> 16) | (fu(s1) & 0xffff0000u);
        unsigned int p3b = (fu(s2) >> 16) | (fu(s3) & 0xffff0000u);
        const int off = slot * 512 + er * 8 + sub * 4;   // ushort units
        *(uint2*)(void*)(base + off)          = make_uint2(p1a, p1b);
        *(uint2*)(void*)(base + 2048 + off)   = make_uint2(p2a, p2b);
        *(uint2*)(void*)(base + 4096 + off)   = make_uint2(p3a, p3b);
    };

    // ---- one K-chunk of MFMAs: 6 limb-products per C-tile
    auto compute = [&](int buf) {
        const float* xb          = xsBase + buf * 4096;
        const unsigned short* wb = wsBase + buf * 6144;
        bf16x8 Bf[2][3];
        #pragma unroll
        for (int cc = 0; cc < 2; ++cc) {
            const int er = eh * 32 + cc * 16 + eL;
            #pragma unroll
            for (int p = 0; p < 3; ++p)
                Bf[cc][p] = *(const bf16x8*)(const void*)(wb + p * 2048 + q * 512 + er * 8);
        }
        #pragma unroll
        for (int tt = 0; tt < 2; ++tt) {
            const int row = tg * 32 + tt * 16 + eL;
            const int sl  = (2 * q) ^ (eL & 7);
            const float4 aL = *(const float4*)&xb[row * 32 + 4 * sl];        // k = 8q..8q+3
            const float4 aH = *(const float4*)&xb[row * 32 + 4 * (sl ^ 1)];  // k = 8q+4..8q+7
            U4 A1, A2, A3;
            const float e0[8] = {aL.x, aL.y, aL.z, aL.w, aH.x, aH.y, aH.z, aH.w};
            #pragma unroll
            for (int m = 0; m < 4; ++m) {
                float x0 = e0[2*m], x1 = e0[2*m+1];
                unsigned int u0 = fu(x0), u1 = fu(x1);
                A1.u[m] = (u0 >> 16) | (u1 & 0xffff0000u);
                float r0 = x0 - uf(u0 & 0xffff0000u), r1 = x1 - uf(u1 & 0xffff0000u);
                unsigned int w0 = fu(r0), w1 = fu(r1);
                A2.u[m] = (w0 >> 16) | (w1 & 0xffff0000u);
                float s0 = r0 - uf(w0 & 0xffff0000u), s1 = r1 - uf(w1 & 0xffff0000u);
                A3.u[m] = (fu(s0) >> 16) | (fu(s1) & 0xffff0000u);
            }
            #pragma unroll
            for (int cc = 0; cc < 2; ++cc) {
                const int t = tt * 2 + cc;
                am[t] = __builtin_amdgcn_mfma_f32_16x16x32_bf16(A1.v, Bf[cc][0], am[t], 0,0,0);
                ac[t] = __builtin_amdgcn_mfma_f32_16x16x32_bf16(A1.v, Bf[cc][1], ac[t], 0,0,0);
                ac[t] = __builtin_amdgcn_mfma_f32_16x16x32_bf16(A2.v, Bf[cc][0], ac[t], 0,0,0);
                ac[t] = __builtin_amdgcn_mfma_f32_16x16x32_bf16(A1.v, Bf[cc][2], ac[t], 0,0,0);
                ac[t] = __builtin_amdgcn_mfma_f32_16x16x32_bf16(A2.v, Bf[cc][1], ac[t], 0,0,0);
                ac[t] = __builtin_amdgcn_mfma_f32_16x16x32_bf16(A3.v, Bf[cc][0], ac[t], 0,0,0);
            }
        }
    };

    // ---- main pipeline: prefetch next chunk, compute current, 1 barrier/chunk
    stageX(0, 0);
    putW(loadW(0), 0);
    __syncthreads();
    for (int ch = 0; ch < NCH; ++ch) {
        const int cur = ch & 1;
        const bool pf = (ch + 1 < NCH);
        float4 nw;
        if (pf) { stageX(ch + 1, cur ^ 1); nw = loadW(ch + 1); }
        compute(cur);
        if (pf) putW(nw, cur ^ 1);
        __syncthreads();
    }

    // ---- logits -> LDS (f32, +bias). C layout: col = lane&15, row = (lane>>4)*4 + reg.
    float* probs = out;
    float* idxo  = out + (size_t)NTOK * NEXP;
    const float bb0 = Bv[eh * 32 + eL];
    const float bb1 = Bv[eh * 32 + 16 + eL];
    #pragma unroll
    for (int tt = 0; tt < 2; ++tt)
        #pragma unroll
        for (int cc = 0; cc < 2; ++cc) {
            const int t = tt * 2 + cc;
            const int e = eh * 32 + cc * 16 + eL;
            const float bbv = cc ? bb1 : bb0;
            #pragma unroll
            for (int i = 0; i < 4; ++i) {
                const int r = tg * 32 + tt * 16 + q * 4 + i;
                lg[r * 66 + e] = (am[t][i] + ac[t][i]) + bbv;
            }
        }
    __syncthreads();

    // ---- whole-wave exact f64 redo for margin-critical tokens
    auto slowToken = [&](int Tg) {
        const float* xr = X + (size_t)Tg * EMB;
        const float* wr = W + (size_t)lane * EMB;
        double ex = (double)Bv[lane];
        for (int k = 0; k < EMB; k += 4) {
            const float4 xv = *(const float4*)&xr[k];
            const float4 wv = *(const float4*)&wr[k];
            ex += (double)xv.x * (double)wv.x;
            ex += (double)xv.y * (double)wv.y;
            ex += (double)xv.z * (double)wv.z;
            ex += (double)xv.w * (double)wv.w;
        }
        bool selb = false; int myrank = 0;
        double m0d = 0.0; float ss = 0.f;
        #pragma unroll
        for (int it = 0; it < TOPK; ++it) {
            double bv = selb ? -1.0e300 : ex; int be = lane;
            #pragma unroll
            for (int off = 1; off <= 32; off <<= 1) {
                const double ov = __shfl_xor(bv, off, 64);
                const int    oe = __shfl_xor(be, off, 64);
                if (ov > bv || (ov == bv && oe < be)) { bv = ov; be = oe; }
            }
            if (it == 0) m0d = bv;
            ss += __expf((float)(bv - m0d));
            if (lane == be) { selb = true; myrank = it; }
        }
        probs[(size_t)Tg * NEXP + lane] = selb ? __expf((float)(ex - m0d)) / ss : 0.f;
        if (selb) idxo[(size_t)Tg * TOPK + myrank] = (float)lane;
    };

    // ---- fast top-8 + masked softmax; wave w owns local tokens w*16 .. +15
    #pragma unroll
    for (int i = 0; i < 4; ++i) {
        const int T = w * 16 + q * 4 + i;       // local token
        float v[4];
        #pragma unroll
        for (int c = 0; c < 4; ++c) v[c] = lg[T * 66 + c * 16 + eL];

        unsigned sel = 0;
        float m0 = 0.f, ssum = 0.f, prev = 0.f, mingap = 1e30f;
        int myIdx = 0;
        #pragma unroll
        for (int it = 0; it <= TOPK; ++it) {    // 9 ranks: need gap to rank-8
            float bv = -1e30f; int be = 1 << 30;
            #pragma unroll
            for (int c = 0; c < 4; ++c)
                if (!((sel >> c) & 1) && v[c] > bv) { bv = v[c]; be = c * 16 + eL; }
            float gv = bv; int ge = be;
            #pragma unroll
            for (int off = 1; off <= 8; off <<= 1) {
                const float ov = __shfl_xor(gv, off, 64);
                const int   oe = __shfl_xor(ge, off, 64);
                if (ov > gv || (ov == gv && oe < ge)) { gv = ov; ge = oe; }
            }
            if (it == 0) m0 = gv;
            else mingap = fminf(mingap, prev - gv);
            prev = gv;
            if (it < TOPK) {
                ssum += __expf(gv - m0);
                if ((ge & 15) == eL) sel |= 1u << (ge >> 4);
                if (eL == it) myIdx = ge;
            }
        }
        const int Tg = t0 + T;
        const float inv = 1.0f / ssum;
        #pragma unroll
        for (int c = 0; c < 4; ++c) {
            const float p = ((sel >> c) & 1) ? __expf(v[c] - m0) * inv : 0.0f;
            probs[(size_t)Tg * NEXP + c * 16 + eL] = p;
        }
        if (eL < TOPK) idxo[(size_t)Tg * TOPK + eL] = (float)myIdx;

        // margin guard: any adjacent gap among ranks 0..8 below TAU -> exact redo
        const unsigned long long fb = __ballot(mingap < TAU);
        for (int q2 = 0; q2 < 4; ++q2)
            if ((fb >> (q2 * 16)) & 1) slowToken(t0 + w * 16 + q2 * 4 + i);
    }
}

extern "C" void kernel_launch(void* const* d_in, const int* in_sizes, int n_in,
                              void* d_out, int out_size, void* d_ws, size_t ws_size,
                              hipStream_t stream) {
    const float* X = (const float*)d_in[0];
    const float* W = (const float*)d_in[1];
    const float* B = (const float*)d_in[2];
    router_bf16x3<<<NTOK / BT, 512, 0, stream>>>(X, W, B, (float*)d_out);
}

// Round 3
// 484.867 us; speedup vs baseline: 1.0478x; 1.0478x over previous
//
#include <hip/hip_runtime.h>
#include <cmath>

#define NTOK 32768   // 8*4096 tokens
#define EMB  2048
#define NEXP 64
#define TOPK 8
#define BT   64      // tokens per block -> grid 512 = 2 blocks/CU
#define KC   32      // K per chunk = MFMA K
#define NCH  (EMB / KC)   // 64
#define TAU  1e-4f   // exact-recompute margin (~60 sigma of limb-GEMM error)

typedef __attribute__((ext_vector_type(8))) short bf16x8;   // 8 bf16 (4 VGPRs)
typedef __attribute__((ext_vector_type(4))) float f32x4;

union U4 { unsigned int u[4]; bf16x8 v; };

__device__ __forceinline__ float uf(unsigned int x) { return __uint_as_float(x); }
__device__ __forceinline__ unsigned int fu(float x) { return __float_as_uint(x); }

__device__ __forceinline__ void gld16(const float* g, float* lds) {
    __builtin_amdgcn_global_load_lds(
        (const __attribute__((address_space(1))) void*)g,
        (__attribute__((address_space(3))) void*)lds,
        16, 0, 0);
}

// LDS map (40 KB static):
//   xs[2][64][32] f32    @ 0      (2 x 8 KB)   X chunk, 16B-granule swizzled via global src
//   ws[2][3][4][64][8] u16 @ 16384 (2 x 12 KB) W bf16 limb planes, k-slot-major
//   lg[64][66] f32       @ 0      (16896 B)    epilogue logits (aliases xs + 512B of ws buf0;
//                                              safe: written only after final chunk barrier)
__global__ __launch_bounds__(512, 2) void router_bf16x3(
    const float* __restrict__ X,   // [NTOK][EMB]
    const float* __restrict__ W,   // [NEXP][EMB]
    const float* __restrict__ Bv,  // [NEXP]
    float* __restrict__ out)       // probs [NTOK][64], then indices [NTOK][8] as f32
{
    __shared__ __align__(16) unsigned char smem[40960];
    float* xsBase          = (float*)smem;                       // + buf*2048 floats
    unsigned short* wsBase = (unsigned short*)(smem + 16384);    // + buf*6144 ushorts
    float* lg              = (float*)smem;                       // [64][66]

    const int tid  = threadIdx.x;
    const int lane = tid & 63;
    const int w    = tid >> 6;     // 0..7
    const int tg   = w >> 1;       // token group: rows tg*16 .. +15
    const int eh   = w & 1;        // expert half: cols eh*32 .. +31
    const int eL   = lane & 15;
    const int q    = lane >> 4;
    const int t0   = blockIdx.x * BT;

    f32x4 am[2], ac[2];            // per-cc head acc + correction acc
    #pragma unroll
    for (int t = 0; t < 2; ++t) {
        am[t] = (f32x4){0.f, 0.f, 0.f, 0.f};
        ac[t] = (f32x4){0.f, 0.f, 0.f, 0.f};
    }

    // ---- X stage: global_load_lds, dest linear [row][slot], source granule-swizzled
    //      LDS[row][slot] = G[row][slot ^ (row&7)]; 1 instr per wave (8 rows each).
    auto stageX = [&](int ch, int buf) {
        const int kc0 = ch * KC;
        float* dst = xsBase + buf * 2048;
        const int row = w * 8 + (lane >> 3);
        const int g   = (lane & 7) ^ (lane >> 3);   // src 16B granule (row&7 == lane>>3)
        gld16(&X[(size_t)(t0 + row) * EMB + kc0 + 4 * g], dst + w * 256);
    };

    // ---- W stage: 1 float4 per thread; split to 3 bf16 limbs; k-slot-major LDS layout
    auto loadW = [&](int ch) -> float4 {
        const int er = tid >> 3;                      // expert row 0..63
        const int h  = tid & 7;                       // 4-f32 granule 0..7
        return *(const float4*)&W[(size_t)er * EMB + ch * KC + 4 * h];
    };
    auto putW = [&](float4 v, int buf) {
        const int er = tid >> 3, h = tid & 7, slot = h >> 1, sub = h & 1;
        unsigned short* base = wsBase + buf * 6144;
        unsigned int u0 = fu(v.x), u1 = fu(v.y), u2 = fu(v.z), u3 = fu(v.w);
        unsigned int p1a = (u0 >> 16) | (u1 & 0xffff0000u);
        unsigned int p1b = (u2 >> 16) | (u3 & 0xffff0000u);
        float r0 = v.x - uf(u0 & 0xffff0000u), r1 = v.y - uf(u1 & 0xffff0000u);
        float r2 = v.z - uf(u2 & 0xffff0000u), r3 = v.w - uf(u3 & 0xffff0000u);
        unsigned int w0 = fu(r0), w1 = fu(r1), w2 = fu(r2), w3 = fu(r3);
        unsigned int p2a = (w0 >> 16) | (w1 & 0xffff0000u);
        unsigned int p2b = (w2 >> 16) | (w3 & 0xffff0000u);
        float s0 = r0 - uf(w0 & 0xffff0000u), s1 = r1 - uf(w1 & 0xffff0000u);
        float s2 = r2 - uf(w2 & 0xffff0000u), s3 = r3 - uf(w3 & 0xffff0000u);
        unsigned int p3a = (fu(s0) >> 16) | (fu(s1) & 0xffff0000u);
        unsigned int p3b = (fu(s2) >> 16) | (fu(s3) & 0xffff0000u);
        const int off = slot * 512 + er * 8 + sub * 4;   // ushort units
        *(uint2*)(void*)(base + off)          = make_uint2(p1a, p1b);
        *(uint2*)(void*)(base + 2048 + off)   = make_uint2(p2a, p2b);
        *(uint2*)(void*)(base + 4096 + off)   = make_uint2(p3a, p3b);
    };

    // ---- one K-chunk of MFMAs: 6 limb-products per C-tile, 12 MFMA/wave
    auto compute = [&](int buf) {
        const float* xb          = xsBase + buf * 2048;
        const unsigned short* wb = wsBase + buf * 6144;
        bf16x8 Bf[2][3];
        #pragma unroll
        for (int cc = 0; cc < 2; ++cc) {
            const int er = eh * 32 + cc * 16 + eL;
            #pragma unroll
            for (int p = 0; p < 3; ++p)
                Bf[cc][p] = *(const bf16x8*)(const void*)(wb + p * 2048 + q * 512 + er * 8);
        }
        const int row = tg * 16 + eL;
        const int sl  = (2 * q) ^ (eL & 7);
        const float4 aL = *(const float4*)&xb[row * 32 + 4 * sl];        // k = 8q..8q+3
        const float4 aH = *(const float4*)&xb[row * 32 + 4 * (sl ^ 1)];  // k = 8q+4..8q+7
        U4 A1, A2, A3;
        const float e0[8] = {aL.x, aL.y, aL.z, aL.w, aH.x, aH.y, aH.z, aH.w};
        #pragma unroll
        for (int m = 0; m < 4; ++m) {
            float x0 = e0[2*m], x1 = e0[2*m+1];
            unsigned int u0 = fu(x0), u1 = fu(x1);
            A1.u[m] = (u0 >> 16) | (u1 & 0xffff0000u);
            float r0 = x0 - uf(u0 & 0xffff0000u), r1 = x1 - uf(u1 & 0xffff0000u);
            unsigned int w0 = fu(r0), w1 = fu(r1);
            A2.u[m] = (w0 >> 16) | (w1 & 0xffff0000u);
            float s0 = r0 - uf(w0 & 0xffff0000u), s1 = r1 - uf(w1 & 0xffff0000u);
            A3.u[m] = (fu(s0) >> 16) | (fu(s1) & 0xffff0000u);
        }
        #pragma unroll
        for (int cc = 0; cc < 2; ++cc) {
            am[cc] = __builtin_amdgcn_mfma_f32_16x16x32_bf16(A1.v, Bf[cc][0], am[cc], 0,0,0);
            ac[cc] = __builtin_amdgcn_mfma_f32_16x16x32_bf16(A1.v, Bf[cc][1], ac[cc], 0,0,0);
            ac[cc] = __builtin_amdgcn_mfma_f32_16x16x32_bf16(A2.v, Bf[cc][0], ac[cc], 0,0,0);
            ac[cc] = __builtin_amdgcn_mfma_f32_16x16x32_bf16(A1.v, Bf[cc][2], ac[cc], 0,0,0);
            ac[cc] = __builtin_amdgcn_mfma_f32_16x16x32_bf16(A2.v, Bf[cc][1], ac[cc], 0,0,0);
            ac[cc] = __builtin_amdgcn_mfma_f32_16x16x32_bf16(A3.v, Bf[cc][0], ac[cc], 0,0,0);
        }
    };

    // ---- main pipeline: prefetch next chunk, compute current, 1 barrier/chunk
    stageX(0, 0);
    putW(loadW(0), 0);
    __syncthreads();
    for (int ch = 0; ch < NCH; ++ch) {
        const int cur = ch & 1;
        const bool pf = (ch + 1 < NCH);
        float4 nw;
        if (pf) { stageX(ch + 1, cur ^ 1); nw = loadW(ch + 1); }
        compute(cur);
        if (pf) putW(nw, cur ^ 1);
        __syncthreads();
    }

    // ---- logits -> LDS (f32, +bias). C layout: col = lane&15, row = (lane>>4)*4 + reg.
    float* probs = out;
    float* idxo  = out + (size_t)NTOK * NEXP;
    const float bb0 = Bv[eh * 32 + eL];
    const float bb1 = Bv[eh * 32 + 16 + eL];
    #pragma unroll
    for (int cc = 0; cc < 2; ++cc) {
        const int e = eh * 32 + cc * 16 + eL;
        const float bbv = cc ? bb1 : bb0;
        #pragma unroll
        for (int i = 0; i < 4; ++i) {
            const int r = tg * 16 + q * 4 + i;
            lg[r * 66 + e] = (am[cc][i] + ac[cc][i]) + bbv;
        }
    }
    __syncthreads();

    // ---- whole-wave exact f64 redo for margin-critical tokens.
    // Unrolled x16, 4 independent accumulators: 8 loads in flight -> latency-pipelined
    // (~3.5us/token vs ~64us for the serial-dependent version).
    auto slowToken = [&](int Tg) {
        const float* xr = X + (size_t)Tg * EMB;
        const float* wr = W + (size_t)lane * EMB;
        double s0 = 0.0, s1 = 0.0, s2 = 0.0, s3 = 0.0;
        for (int k = 0; k < EMB; k += 16) {
            const float4 xa = *(const float4*)&xr[k];
            const float4 xb = *(const float4*)&xr[k + 4];
            const float4 xc = *(const float4*)&xr[k + 8];
            const float4 xd = *(const float4*)&xr[k + 12];
            const float4 wa = *(const float4*)&wr[k];
            const float4 wb = *(const float4*)&wr[k + 4];
            const float4 wc = *(const float4*)&wr[k + 8];
            const float4 wd = *(const float4*)&wr[k + 12];
            s0 += (double)xa.x * wa.x + (double)xa.y * wa.y
                + (double)xa.z * wa.z + (double)xa.w * wa.w;
            s1 += (double)xb.x * wb.x + (double)xb.y * wb.y
                + (double)xb.z * wb.z + (double)xb.w * wb.w;
            s2 += (double)xc.x * wc.x + (double)xc.y * wc.y
                + (double)xc.z * wc.z + (double)xc.w * wc.w;
            s3 += (double)xd.x * wd.x + (double)xd.y * wd.y
                + (double)xd.z * wd.z + (double)xd.w * wd.w;
        }
        double ex = (double)Bv[lane] + ((s0 + s1) + (s2 + s3));
        bool selb = false; int myrank = 0;
        double m0d = 0.0; float ss = 0.f;
        #pragma unroll
        for (int it = 0; it < TOPK; ++it) {
            double bv = selb ? -1.0e300 : ex; int be = lane;
            #pragma unroll
            for (int off = 1; off <= 32; off <<= 1) {
                const double ov = __shfl_xor(bv, off, 64);
                const int    oe = __shfl_xor(be, off, 64);
                if (ov > bv || (ov == bv && oe < be)) { bv = ov; be = oe; }
            }
            if (it == 0) m0d = bv;
            ss += __expf((float)(bv - m0d));
            if (lane == be) { selb = true; myrank = it; }
        }
        probs[(size_t)Tg * NEXP + lane] = selb ? __expf((float)(ex - m0d)) / ss : 0.f;
        if (selb) idxo[(size_t)Tg * TOPK + myrank] = (float)lane;
    };

    // ---- fast top-8 + masked softmax; wave w owns local tokens w*8 .. +7
    #pragma unroll
    for (int i = 0; i < 2; ++i) {
        const int T = w * 8 + i * 4 + q;        // local token (one per 16-lane group)
        float v[4];
        #pragma unroll
        for (int c = 0; c < 4; ++c) v[c] = lg[T * 66 + c * 16 + eL];

        unsigned sel = 0;
        float m0 = 0.f, ssum = 0.f, prev = 0.f, mingap = 1e30f;
        int myIdx = 0;
        #pragma unroll
        for (int it = 0; it <= TOPK; ++it) {    // 9 ranks: need gap to rank-8
            float bv = -1e30f; int be = 1 << 30;
            #pragma unroll
            for (int c = 0; c < 4; ++c)
                if (!((sel >> c) & 1) && v[c] > bv) { bv = v[c]; be = c * 16 + eL; }
            float gv = bv; int ge = be;
            #pragma unroll
            for (int off = 1; off <= 8; off <<= 1) {
                const float ov = __shfl_xor(gv, off, 64);
                const int   oe = __shfl_xor(ge, off, 64);
                if (ov > gv || (ov == gv && oe < ge)) { gv = ov; ge = oe; }
            }
            if (it == 0) m0 = gv;
            else mingap = fminf(mingap, prev - gv);
            prev = gv;
            if (it < TOPK) {
                ssum += __expf(gv - m0);
                if ((ge & 15) == eL) sel |= 1u << (ge >> 4);
                if (eL == it) myIdx = ge;
            }
        }
        const int Tg = t0 + T;
        const float inv = 1.0f / ssum;
        #pragma unroll
        for (int c = 0; c < 4; ++c) {
            const float p = ((sel >> c) & 1) ? __expf(v[c] - m0) * inv : 0.0f;
            probs[(size_t)Tg * NEXP + c * 16 + eL] = p;
        }
        if (eL < TOPK) idxo[(size_t)Tg * TOPK + eL] = (float)myIdx;

        // margin guard: any adjacent gap among ranks 0..8 below TAU -> exact redo
        const unsigned long long fb = __ballot(mingap < TAU);
        for (int q2 = 0; q2 < 4; ++q2)
            if ((fb >> (q2 * 16)) & 1) slowToken(t0 + w * 8 + i * 4 + q2);
    }
}

extern "C" void kernel_launch(void* const* d_in, const int* in_sizes, int n_in,
                              void* d_out, int out_size, void* d_ws, size_t ws_size,
                              hipStream_t stream) {
    const float* X = (const float*)d_in[0];
    const float* W = (const float*)d_in[1];
    const float* B = (const float*)d_in[2];
    router_bf16x3<<<NTOK / BT, 512, 0, stream>>>(X, W, B, (float*)d_out);
}